// Round 2
// baseline (351.576 us; speedup 1.0000x reference)
//
#include <hip/hip_runtime.h>

// ---------------- problem constants ----------------
#define NG      19
#define HEIGHT  256
#define WIDTH   512
#define HW      (HEIGHT*WIDTH)        // 131072
#define BATCH   4
#define TH      16                    // tile rows
#define TW      64                    // tile cols
#define HALO_R  (TH+2)                // 18
#define HALO_C  (TW+2)                // 66
#define LSTRIDE 67                    // odd stride -> 2-way max bank aliasing (free)
#define CH_STRIDE (HALO_R*LSTRIDE)    // 1206
#define LDS_FLOATS (5*CH_STRIDE)      // 6030 floats = 24120 B
#define WXF_FLOATS (NG*4*15*12)       // 13680 transformed weights
#define BIAS_FLOATS (NG*16)           // 304 permuted biases

// Weight transform:
//   src  W[(g*16 + gate*4 + s)][ic][kr][kc]   (304,5,3,3)
//   dst  [g][s][ic][kr][gate][kc]  -> per (g,s,ic,kr) the 12 floats used in
//   one inner step are contiguous & 16B-aligned => uniform s_load_dwordx4.
// Bias permuted to [g][s][gate].
__global__ void wxform_kernel(const float* __restrict__ W,
                              const float* __restrict__ b,
                              float* __restrict__ dst) {
    int i = blockIdx.x * 256 + threadIdx.x;
    if (i < WXF_FLOATS) {
        int g  = i / 720;  int r = i % 720;
        int s  = r / 180;  r %= 180;
        int ic = r / 36;   r %= 36;
        int kr = r / 12;   r %= 12;
        int gate = r / 3;  int kc = r % 3;
        dst[i] = W[(((g*16 + gate*4 + s)*5 + ic)*3 + kr)*3 + kc];
    } else if (i < WXF_FLOATS + BIAS_FLOATS) {
        int j = i - WXF_FLOATS;
        int g = j / 16;  int r = j % 16;
        int s = r / 4;   int gate = r % 4;
        dst[i] = b[g*16 + gate*4 + s];
    }
}

__device__ __forceinline__ float fsigmoid(float x) {
    return __builtin_amdgcn_rcpf(1.0f + __builtin_amdgcn_exp2f(-1.44269504f * x));
}
__device__ __forceinline__ float ftanh(float x) {
    return 2.0f * __builtin_amdgcn_rcpf(1.0f + __builtin_amdgcn_exp2f(-2.88539008f * x)) - 1.0f;
}

__launch_bounds__(256, 4)
__global__ void convlstm_kernel(const float* __restrict__ x,
                                const float* __restrict__ h,
                                const float* __restrict__ c,
                                const float* __restrict__ wt,   // transformed weights (+bias tail)
                                float* __restrict__ out) {
    __shared__ float lds[LDS_FLOATS];

    const int t    = threadIdx.x;
    const int bid  = blockIdx.x;
    const int bg   = bid >> 7;          // (b*19+g), 128 tiles per image plane
    const int tile = bid & 127;
    const int tr0  = (tile >> 3) * TH;  // 16 row-tiles
    const int tc0  = (tile & 7)  * TW;  // 8 col-tiles
    const int g    = bg % NG;

    // ---- stage 5-channel halo tile (18 x 66) into LDS, zero-padded ----
    const float* xbase = x + bg * HW;
    const float* hbase = h + (bg * 4) * HW;
    const int total = 5 * HALO_R * HALO_C;  // 5940
    for (int f = t; f < total; f += 256) {
        int ch  = f / (HALO_R * HALO_C);
        int rem = f - ch * (HALO_R * HALO_C);
        int r   = rem / HALO_C;
        int cc  = rem - r * HALO_C;
        int gr  = tr0 + r - 1;
        int gc  = tc0 + cc - 1;
        float v = 0.0f;
        if (gr >= 0 && gr < HEIGHT && gc >= 0 && gc < WIDTH) {
            const float* base = (ch == 0) ? xbase : (hbase + (ch - 1) * HW);
            v = base[gr * WIDTH + gc];
        }
        lds[ch * CH_STRIDE + r * LSTRIDE + cc] = v;
    }
    __syncthreads();

    // ---- each thread: 4 consecutive pixels; ONE SLAB AT A TIME (acc = 16 regs) ----
    const int rl = t >> 4;          // 0..15
    const int cl = (t & 15) << 2;   // 0,4,...,60
    const int pixbase = (tr0 + rl) * WIDTH + (tc0 + cl);
    const int NC_OFF  = BATCH * NG * 4 * HW;   // 39,845,888

    const float* bt = wt + WXF_FLOATS;

    #pragma unroll 1
    for (int s = 0; s < 4; ++s) {
        const float* wgs = wt + (g * 4 + s) * 180;   // 15 * 12 floats
        const float* bgs = bt + (g * 4 + s) * 4;

        float acc[4][4];
        #pragma unroll
        for (int gate = 0; gate < 4; ++gate) {
            float bv = bgs[gate];
            #pragma unroll
            for (int p = 0; p < 4; ++p) acc[gate][p] = bv;
        }

        #pragma unroll
        for (int ic = 0; ic < 5; ++ic) {
            #pragma unroll
            for (int kr = 0; kr < 3; ++kr) {
                const float* lrow = lds + ic * CH_STRIDE + (rl + kr) * LSTRIDE + cl;
                float v0 = lrow[0], v1 = lrow[1], v2 = lrow[2];
                float v3 = lrow[3], v4 = lrow[4], v5 = lrow[5];
                const float* wr = wgs + (ic * 3 + kr) * 12;  // uniform, 16B-aligned
                #pragma unroll
                for (int gate = 0; gate < 4; ++gate) {
                    float w0 = wr[gate*3 + 0];
                    float w1 = wr[gate*3 + 1];
                    float w2 = wr[gate*3 + 2];
                    acc[gate][0] = fmaf(v0, w0, fmaf(v1, w1, fmaf(v2, w2, acc[gate][0])));
                    acc[gate][1] = fmaf(v1, w0, fmaf(v2, w1, fmaf(v3, w2, acc[gate][1])));
                    acc[gate][2] = fmaf(v2, w0, fmaf(v3, w1, fmaf(v4, w2, acc[gate][2])));
                    acc[gate][3] = fmaf(v3, w0, fmaf(v4, w1, fmaf(v5, w2, acc[gate][3])));
                }
            }
        }

        // ---- gates + cell update for this slab, float4 I/O ----
        const int chan = (bg * 4 + s) * HW + pixbase;
        float4 cv = *reinterpret_cast<const float4*>(c + chan);
        float cvx[4] = {cv.x, cv.y, cv.z, cv.w};
        float nhv[4], ncv[4];
        #pragma unroll
        for (int p = 0; p < 4; ++p) {
            float iv = fsigmoid(acc[0][p]);
            float fv = fsigmoid(acc[1][p]);
            float ov = fsigmoid(acc[2][p]);
            float gv = ftanh   (acc[3][p]);
            float nc = fv * cvx[p] + iv * gv;
            ncv[p] = nc;
            nhv[p] = ov * ftanh(nc);
        }
        *reinterpret_cast<float4*>(out + chan) =
            make_float4(nhv[0], nhv[1], nhv[2], nhv[3]);
        *reinterpret_cast<float4*>(out + NC_OFF + chan) =
            make_float4(ncv[0], ncv[1], ncv[2], ncv[3]);
    }
}

extern "C" void kernel_launch(void* const* d_in, const int* in_sizes, int n_in,
                              void* d_out, int out_size, void* d_ws, size_t ws_size,
                              hipStream_t stream) {
    (void)in_sizes; (void)n_in; (void)out_size; (void)ws_size;
    const float* x = (const float*)d_in[0];
    const float* h = (const float*)d_in[1];
    const float* c = (const float*)d_in[2];
    const float* W = (const float*)d_in[3];
    const float* b = (const float*)d_in[4];
    float* out = (float*)d_out;
    float* wt  = (float*)d_ws;   // 13680 + 304 floats of scratch

    hipLaunchKernelGGL(wxform_kernel,
                       dim3((WXF_FLOATS + BIAS_FLOATS + 255) / 256), dim3(256),
                       0, stream, W, b, wt);
    hipLaunchKernelGGL(convlstm_kernel, dim3(BATCH * NG * 128), dim3(256),
                       0, stream, x, h, c, wt, out);
}

// Round 3
// 229.395 us; speedup vs baseline: 1.5326x; 1.5326x over previous
//
#include <hip/hip_runtime.h>
#include <hip/hip_bf16.h>

// ---------------- problem constants ----------------
#define NG      19
#define HEIGHT  256
#define WIDTH   512
#define HW      (HEIGHT*WIDTH)        // 131072
#define BATCH   4
#define TH      16                    // tile rows
#define TW      64                    // tile cols
#define HALO_R  18
#define HALO_C  68                    // 66 real halo cols + 2 pad (finite, staged)
#define CH_STRIDE (HALO_R*HALO_C)     // 1224
#define LDS_FLOATS (5*CH_STRIDE)      // 6120 floats = 24480 B
#define WFRAG_SHORTS (NG*64*16)       // per-lane packed A fragments, bf16
#define BIAS_FLOATS (NG*16)

typedef __attribute__((ext_vector_type(8))) short short8;
typedef __attribute__((ext_vector_type(4))) float f32x4;

static __device__ __forceinline__ short f2bf(float f) {
    return __builtin_bit_cast(short, __float2bfloat16(f));
}

__device__ __forceinline__ float fsigmoid(float x) {
    return __builtin_amdgcn_rcpf(1.0f + __builtin_amdgcn_exp2f(-1.44269504f * x));
}
__device__ __forceinline__ float ftanh(float x) {
    return 2.0f * __builtin_amdgcn_rcpf(1.0f + __builtin_amdgcn_exp2f(-2.88539008f * x)) - 1.0f;
}

// K-dim enumeration: k = (ic*3+kr)*4 + kc, kc in 0..3; kc==3 and k>=60 are
// zero-weight pad slots (B value junk-but-finite, weight 0).
// A row m = oc_perm = s*4 + gate  -> D gives lane-local gates per (pixel,slab).
// A fragment layout (mfma_f32_16x16x32_bf16): lane l holds row (l&15),
// k = (l>>4)*8 + j (first mfma), +32 (second). Packed per lane: 16 bf16.
__global__ void wxform_kernel(const float* __restrict__ W,
                              const float* __restrict__ b,
                              short* __restrict__ wdst,
                              float* __restrict__ bdst) {
    int i = blockIdx.x * 256 + threadIdx.x;
    if (i < WFRAG_SHORTS) {
        int g   = i / 1024;
        int r   = i & 1023;
        int l   = r >> 4;          // lane 0..63
        int j   = r & 15;          // element 0..15 (j>>3 = which mfma)
        int q   = l >> 4;
        int row = l & 15;          // oc_perm = s*4 + gate
        int s    = row >> 2;
        int gate = row & 3;
        int half = j >> 3;
        int jj   = j & 7;
        int m  = 8*half + 2*q + (jj >> 2);   // (ic,kr) combo index
        int kc = jj & 3;
        float wv = 0.0f;
        if (m <= 14 && kc < 3) {
            int ic = m / 3, kr = m % 3;
            int oc = g*16 + gate*4 + s;
            wv = W[((oc*5 + ic)*3 + kr)*3 + kc];
        }
        wdst[i] = f2bf(wv);
    } else if (i < WFRAG_SHORTS + BIAS_FLOATS) {
        int idx = i - WFRAG_SHORTS;
        int g = idx >> 4;
        int r = idx & 15;
        int s = r >> 2, gate = r & 3;
        bdst[idx] = b[g*16 + gate*4 + s];   // [g][s][gate]
    }
}

__launch_bounds__(256, 4)
__global__ void convlstm_mfma(const float* __restrict__ x,
                              const float* __restrict__ h,
                              const float* __restrict__ c,
                              const short* __restrict__ wfrag,
                              const float* __restrict__ biasp,
                              float* __restrict__ out) {
    __shared__ float lds[LDS_FLOATS];

    const int t    = threadIdx.x;
    const int bid  = blockIdx.x;
    const int bg   = bid >> 7;          // (b*19+g)
    const int tile = bid & 127;
    const int tr0  = (tile >> 3) * TH;
    const int tc0  = (tile & 7)  * TW;
    const int g    = bg % NG;

    // ---- stage 5-channel halo tile (18 x 68) fp32, fully initialized ----
    const float* xb = x + bg * HW;
    const float* hb = h + (bg * 4) * HW;
    for (int idx = t; idx < CH_STRIDE; idx += 256) {
        int r  = idx / HALO_C;
        int cc = idx - r * HALO_C;
        int gr = tr0 + r - 1;
        int gc = tc0 + cc - 1;
        bool ok = (gr >= 0 && gr < HEIGHT && gc >= 0 && gc < WIDTH);
        int goff = gr * WIDTH + gc;
        #pragma unroll
        for (int ch = 0; ch < 5; ++ch) {
            float v = 0.0f;
            if (ok) v = (ch == 0) ? xb[goff] : hb[(ch - 1) * HW + goff];
            lds[ch * CH_STRIDE + idx] = v;
        }
    }
    __syncthreads();

    const int w  = t >> 6;     // wave 0..3
    const int l  = t & 63;     // lane
    const int q  = l >> 4;     // lane group = slab
    const int li = l & 15;     // pixel within 16-col chunk

    // A fragments: 16 bf16 per lane, packed by wxform
    const short8* ap = reinterpret_cast<const short8*>(wfrag + (g * 64 + l) * 16);
    const short8 a_lo = ap[0];
    const short8 a_hi = ap[1];

    // bias as accumulator init: acc[i] = bias[g][s=q][gate=i]
    f32x4 bias4;
    {
        float4 bv = *reinterpret_cast<const float4*>(biasp + g * 16 + q * 4);
        bias4[0] = bv.x; bias4[1] = bv.y; bias4[2] = bv.z; bias4[3] = bv.w;
    }

    // per-lane LDS row offsets (floats) for this lane group's 4 (ic,kr) combos
    int offm[4];
    #pragma unroll
    for (int i = 0; i < 4; ++i) {
        int m = (i < 2) ? (2*q + i) : (8 + 2*q + (i - 2));
        if (m > 14) m = 14;                       // k>=60 pad: weight is 0
        offm[i] = (m / 3) * CH_STRIDE + (m % 3) * HALO_C;
    }

    const int NC_OFF = BATCH * NG * 4 * HW;   // 39,845,888

    for (int si = 0; si < 16; ++si) {
        const int tr  = w * 4 + (si & 3);          // tile row 0..15
        const int tcp = ((si >> 2) << 4) + li;     // tile col 0..63
        const int base = tr * HALO_C + tcp;

        // issue c-load early
        const int gr   = tr0 + tr;
        const int gc   = tc0 + tcp;
        const int chan = (bg * 4 + q) * HW + gr * WIDTH + gc;
        const float cv = c[chan];

        // B fragments: 4 row-gathers of 4 contiguous floats -> bf16
        short8 blo, bhi;
        {
            const float* p0 = lds + offm[0] + base;
            blo[0]=f2bf(p0[0]); blo[1]=f2bf(p0[1]); blo[2]=f2bf(p0[2]); blo[3]=f2bf(p0[3]);
            const float* p1 = lds + offm[1] + base;
            blo[4]=f2bf(p1[0]); blo[5]=f2bf(p1[1]); blo[6]=f2bf(p1[2]); blo[7]=f2bf(p1[3]);
            const float* p2 = lds + offm[2] + base;
            bhi[0]=f2bf(p2[0]); bhi[1]=f2bf(p2[1]); bhi[2]=f2bf(p2[2]); bhi[3]=f2bf(p2[3]);
            const float* p3 = lds + offm[3] + base;
            bhi[4]=f2bf(p3[0]); bhi[5]=f2bf(p3[1]); bhi[6]=f2bf(p3[2]); bhi[7]=f2bf(p3[3]);
        }

        f32x4 acc = bias4;
        acc = __builtin_amdgcn_mfma_f32_16x16x32_bf16(a_lo, blo, acc, 0, 0, 0);
        acc = __builtin_amdgcn_mfma_f32_16x16x32_bf16(a_hi, bhi, acc, 0, 0, 0);

        // lane-local LSTM epilogue: acc = {i,f,o,g} for (pixel, slab=q)
        const float iv = fsigmoid(acc[0]);
        const float fv = fsigmoid(acc[1]);
        const float ov = fsigmoid(acc[2]);
        const float gv = ftanh   (acc[3]);
        const float nc = fv * cv + iv * gv;
        const float nh = ov * ftanh(nc);
        out[chan]          = nh;
        out[NC_OFF + chan] = nc;
    }
}

extern "C" void kernel_launch(void* const* d_in, const int* in_sizes, int n_in,
                              void* d_out, int out_size, void* d_ws, size_t ws_size,
                              hipStream_t stream) {
    (void)in_sizes; (void)n_in; (void)out_size; (void)ws_size;
    const float* x = (const float*)d_in[0];
    const float* h = (const float*)d_in[1];
    const float* c = (const float*)d_in[2];
    const float* W = (const float*)d_in[3];
    const float* b = (const float*)d_in[4];
    float* out = (float*)d_out;

    short* wdst = (short*)d_ws;                                        // 38,912 B
    float* bdst = (float*)((char*)d_ws + WFRAG_SHORTS * sizeof(short)); // +1,216 B

    hipLaunchKernelGGL(wxform_kernel,
                       dim3((WFRAG_SHORTS + BIAS_FLOATS + 255) / 256), dim3(256),
                       0, stream, W, b, wdst, bdst);
    hipLaunchKernelGGL(convlstm_mfma, dim3(BATCH * NG * 128), dim3(256),
                       0, stream, x, h, c, (const short*)wdst, bdst, out);
}

// Round 4
// 150.829 us; speedup vs baseline: 2.3310x; 1.5209x over previous
//
#include <hip/hip_runtime.h>
#include <hip/hip_bf16.h>

// ---------------- problem constants ----------------
#define NG      19
#define HEIGHT  256
#define WIDTH   512
#define HW      (HEIGHT*WIDTH)        // 131072
#define BATCH   4
#define TH      16                    // tile rows
#define TW      64                    // tile cols
#define HALO_R  18
#define HALO_CU 34                    // u32 columns = 68 bf16 cols (66 real + 2 pad)
#define CH_U32  (HALO_R*HALO_CU)      // 612 u32 per channel
#define LDS_U32 (5*CH_U32)            // 3060 u32 = 12240 B
#define WFRAG_SHORTS (NG*64*16)       // per-lane packed A fragments, bf16
#define BIAS_FLOATS (NG*16)

typedef __attribute__((ext_vector_type(8))) short short8;
typedef __attribute__((ext_vector_type(4))) float f32x4;
typedef __attribute__((ext_vector_type(4))) unsigned int u32x4;

static __device__ __forceinline__ unsigned int bfbits(float f) {
    return (unsigned int)__builtin_bit_cast(unsigned short, __float2bfloat16(f));
}
static __device__ __forceinline__ unsigned int fsh16(unsigned int hi, unsigned int lo) {
    // bytes 2..5 of {hi:lo} -> one 16-bit funnel shift (v_alignbit)
    return (unsigned int)((((unsigned long long)hi << 32) | lo) >> 16);
}
__device__ __forceinline__ float fsigmoid(float x) {
    return __builtin_amdgcn_rcpf(1.0f + __builtin_amdgcn_exp2f(-1.44269504f * x));
}
__device__ __forceinline__ float ftanh(float x) {
    return 2.0f * __builtin_amdgcn_rcpf(1.0f + __builtin_amdgcn_exp2f(-2.88539008f * x)) - 1.0f;
}

// K enumeration: k = m*4 + kc, m = (ic*3+kr) in 0..14, kc in 0..3.
// kc==3 and m==15 are zero-weight pad slots.
// A row = oc_perm = s*4 + gate -> D gives lane-local gates per (pixel,slab).
// A fragment (mfma_f32_16x16x32_bf16): lane l holds row (l&15),
// k = (l>>4)*8 + j (first mfma), +32 (second). Packed per lane: 16 bf16.
__global__ void wxform_kernel(const float* __restrict__ W,
                              const float* __restrict__ b,
                              short* __restrict__ wdst,
                              float* __restrict__ bdst) {
    int i = blockIdx.x * 256 + threadIdx.x;
    if (i < WFRAG_SHORTS) {
        int g   = i / 1024;
        int r   = i & 1023;
        int l   = r >> 4;          // lane 0..63
        int j   = r & 15;          // element 0..15
        int q   = l >> 4;
        int row = l & 15;          // oc_perm = s*4 + gate
        int s    = row >> 2;
        int gate = row & 3;
        int half = j >> 3;
        int jj   = j & 7;
        int m  = 8*half + 2*q + (jj >> 2);   // (ic,kr) combo index
        int kc = jj & 3;
        float wv = 0.0f;
        if (m <= 14 && kc < 3) {
            int ic = m / 3, kr = m % 3;
            int oc = g*16 + gate*4 + s;
            wv = W[((oc*5 + ic)*3 + kr)*3 + kc];
        }
        wdst[i] = (short)__builtin_bit_cast(unsigned short, __float2bfloat16(wv));
    } else if (i < WFRAG_SHORTS + BIAS_FLOATS) {
        int idx = i - WFRAG_SHORTS;
        int g = idx >> 4;
        int r = idx & 15;
        int s = r >> 2, gate = r & 3;
        bdst[idx] = b[g*16 + gate*4 + s];   // [g][s][gate]
    }
}

__launch_bounds__(256, 4)
__global__ void convlstm_mfma(const float* __restrict__ x,
                              const float* __restrict__ h,
                              const float* __restrict__ c,
                              const short* __restrict__ wfrag,
                              const float* __restrict__ biasp,
                              float* __restrict__ out) {
    __shared__ unsigned int lds[LDS_U32];   // bf16 pairs

    const int t    = threadIdx.x;
    const int bid  = blockIdx.x;
    const int bg   = bid >> 7;          // (b*19+g)
    const int tile = bid & 127;
    const int tr0  = (tile >> 3) * TH;
    const int tc0  = (tile & 7)  * TW;
    const int g    = bg % NG;

    const int w  = t >> 6;     // wave 0..3 (owns tile rows w*4..w*4+3)
    const int l  = t & 63;
    const int q  = l >> 4;     // slab
    const int li = l & 15;     // B column -> pixel tile-col 4*li + n

    // ---- prefetch all 16 c-values before the barrier (independent of LDS) ----
    const int NC_OFF   = BATCH * NG * 4 * HW;   // 39,845,888
    const int chanbase = (bg*4 + q)*HW + tc0 + 4*li;
    float cpre[16];
    #pragma unroll
    for (int tr4 = 0; tr4 < 4; ++tr4) {
        #pragma unroll
        for (int n = 0; n < 4; ++n)
            cpre[tr4*4 + n] = c[chanbase + (tr0 + w*4 + tr4)*WIDTH + n];
    }

    // ---- A fragments + bias ----
    const short8* ap = reinterpret_cast<const short8*>(wfrag + (g*64 + l)*16);
    const short8 a_lo = ap[0];
    const short8 a_hi = ap[1];
    f32x4 bias4;
    {
        float4 bv = *reinterpret_cast<const float4*>(biasp + g*16 + q*4);
        bias4[0] = bv.x; bias4[1] = bv.y; bias4[2] = bv.z; bias4[3] = bv.w;
    }

    // ---- stage 5-channel halo as packed bf16 pairs (convert once) ----
    const float* xb = x + bg * HW;
    const float* hb = h + (bg * 4) * HW;
    for (int p = t; p < LDS_U32; p += 256) {
        int ch  = p / CH_U32;  int rem = p - ch * CH_U32;
        int r   = rem / HALO_CU;
        int j   = rem - r * HALO_CU;
        int gr  = tr0 + r - 1;
        int gc  = tc0 + 2*j - 1;
        const float* base = (ch == 0) ? xb : hb + (ch - 1) * HW;
        float v0 = 0.0f, v1 = 0.0f;
        if (gr >= 0 && gr < HEIGHT) {
            const float* rowp = base + gr * WIDTH;
            if (gc >= 0 && gc < WIDTH) v0 = rowp[gc];
            if (gc + 1 < WIDTH)        v1 = rowp[gc + 1];   // gc+1 >= 0 always
        }
        lds[p] = bfbits(v0) | (bfbits(v1) << 16);
    }
    __syncthreads();

    // ---- per-lane combo base byte offsets (8B-aligned by construction) ----
    int cbase[4];
    #pragma unroll
    for (int i = 0; i < 4; ++i) {
        int m = (i < 2) ? (2*q + i) : (8 + 2*q + (i - 2));
        if (m > 14) m = 14;                         // m==15 pad: weight is 0
        cbase[i] = (m/3)*(CH_U32*4) + (m%3)*(HALO_CU*4) + 8*li;
    }
    const char* ldsb = reinterpret_cast<const char*>(lds);

    #pragma unroll
    for (int tr4 = 0; tr4 < 4; ++tr4) {
        const int tr = w*4 + tr4;
        // one 16B window read per combo serves all 4 chunks
        uint2 dv[4][2];
        #pragma unroll
        for (int i = 0; i < 4; ++i) {
            const uint2* pp = reinterpret_cast<const uint2*>(
                ldsb + cbase[i] + tr * (HALO_CU*4));
            dv[i][0] = pp[0];       // ds_read_b64: cols 4li..4li+3
            dv[i][1] = pp[1];       // ds_read_b64: cols 4li+4..4li+7
        }
        #pragma unroll
        for (int n = 0; n < 4; ++n) {
            u32x4 blo_u, bhi_u;
            #pragma unroll
            for (int i = 0; i < 4; ++i) {
                const unsigned int d0 = dv[i][0].x, d1 = dv[i][0].y;
                const unsigned int d2 = dv[i][1].x, d3 = dv[i][1].y;
                unsigned int w0, w1;
                if (n == 0)      { w0 = d0;           w1 = d1;           }
                else if (n == 1) { w0 = fsh16(d1,d0); w1 = fsh16(d2,d1); }
                else if (n == 2) { w0 = d1;           w1 = d2;           }
                else             { w0 = fsh16(d2,d1); w1 = fsh16(d3,d2); }
                if (i < 2) { blo_u[2*i]     = w0; blo_u[2*i+1]     = w1; }
                else       { bhi_u[2*(i-2)] = w0; bhi_u[2*(i-2)+1] = w1; }
            }
            const short8 blo = __builtin_bit_cast(short8, blo_u);
            const short8 bhi = __builtin_bit_cast(short8, bhi_u);

            f32x4 acc = bias4;
            acc = __builtin_amdgcn_mfma_f32_16x16x32_bf16(a_lo, blo, acc, 0, 0, 0);
            acc = __builtin_amdgcn_mfma_f32_16x16x32_bf16(a_hi, bhi, acc, 0, 0, 0);

            // lane-local LSTM epilogue: acc = {i,f,o,g} for (pixel, slab=q)
            const float cv = cpre[tr4*4 + n];
            const float iv = fsigmoid(acc[0]);
            const float fv = fsigmoid(acc[1]);
            const float ov = fsigmoid(acc[2]);
            const float gv = ftanh   (acc[3]);
            const float nc = fv * cv + iv * gv;
            const float nh = ov * ftanh(nc);
            const int chan = chanbase + (tr0 + tr)*WIDTH + n;
            out[chan]          = nh;
            out[NC_OFF + chan] = nc;
        }
    }
}

extern "C" void kernel_launch(void* const* d_in, const int* in_sizes, int n_in,
                              void* d_out, int out_size, void* d_ws, size_t ws_size,
                              hipStream_t stream) {
    (void)in_sizes; (void)n_in; (void)out_size; (void)ws_size;
    const float* x = (const float*)d_in[0];
    const float* h = (const float*)d_in[1];
    const float* c = (const float*)d_in[2];
    const float* W = (const float*)d_in[3];
    const float* b = (const float*)d_in[4];
    float* out = (float*)d_out;

    short* wdst = (short*)d_ws;                                         // 38,912 B
    float* bdst = (float*)((char*)d_ws + WFRAG_SHORTS * sizeof(short)); // +1,216 B

    hipLaunchKernelGGL(wxform_kernel,
                       dim3((WFRAG_SHORTS + BIAS_FLOATS + 255) / 256), dim3(256),
                       0, stream, W, b, wdst, bdst);
    hipLaunchKernelGGL(convlstm_mfma, dim3(BATCH * NG * 128), dim3(256),
                       0, stream, x, h, c, (const short*)wdst, bdst, out);
}

// Round 6
// 146.500 us; speedup vs baseline: 2.3998x; 1.0296x over previous
//
#include <hip/hip_runtime.h>
#include <hip/hip_bf16.h>

// ---------------- problem constants ----------------
#define NG      19
#define HEIGHT  256
#define WIDTH   512
#define HW      (HEIGHT*WIDTH)        // 131072
#define BATCH   4
#define TH      16                    // tile rows
#define TW      64                    // tile cols
#define HALO_R  18
#define HALO_CU 34                    // u32 columns = 68 bf16 cols (66 real + 2 pad)
#define CH_U32  (HALO_R*HALO_CU)      // 612 u32 per channel
#define LDS_U32 (5*CH_U32)            // 3060 u32 = 12240 B
#define WFRAG_SHORTS (NG*64*16)       // per-lane packed A fragments, bf16
#define BIAS_FLOATS (NG*16)

typedef __attribute__((ext_vector_type(8))) short short8;
typedef __attribute__((ext_vector_type(4))) float f32x4;
typedef __attribute__((ext_vector_type(4))) unsigned int u32x4;

static __device__ __forceinline__ unsigned int bfbits(float f) {
    return (unsigned int)__builtin_bit_cast(unsigned short, __float2bfloat16(f));
}
static __device__ __forceinline__ unsigned int fsh16(unsigned int hi, unsigned int lo) {
    // bytes 2..5 of {hi:lo} -> one 16-bit funnel shift (v_alignbit)
    return (unsigned int)((((unsigned long long)hi << 32) | lo) >> 16);
}
__device__ __forceinline__ float fsigmoid(float x) {
    return __builtin_amdgcn_rcpf(1.0f + __builtin_amdgcn_exp2f(-1.44269504f * x));
}
__device__ __forceinline__ float ftanh(float x) {
    return 2.0f * __builtin_amdgcn_rcpf(1.0f + __builtin_amdgcn_exp2f(-2.88539008f * x)) - 1.0f;
}

// K enumeration: k = m*4 + kc, m = (ic*3+kr) in 0..14, kc in 0..3.
// kc==3 and m==15 are zero-weight pad slots.
// A row = oc_perm = s*4 + gate -> D gives lane-local gates per (pixel,slab).
// A fragment (mfma_f32_16x16x32_bf16): lane l holds row (l&15),
// k = (l>>4)*8 + j (first mfma), +32 (second). Packed per lane: 16 bf16.
__global__ void wxform_kernel(const float* __restrict__ W,
                              const float* __restrict__ b,
                              short* __restrict__ wdst,
                              float* __restrict__ bdst) {
    int i = blockIdx.x * 256 + threadIdx.x;
    if (i < WFRAG_SHORTS) {
        int g   = i / 1024;
        int r   = i & 1023;
        int l   = r >> 4;          // lane 0..63
        int j   = r & 15;          // element 0..15
        int q   = l >> 4;
        int row = l & 15;          // oc_perm = s*4 + gate
        int s    = row >> 2;
        int gate = row & 3;
        int half = j >> 3;
        int jj   = j & 7;
        int m  = 8*half + 2*q + (jj >> 2);   // (ic,kr) combo index
        int kc = jj & 3;
        float wv = 0.0f;
        if (m <= 14 && kc < 3) {
            int ic = m / 3, kr = m % 3;
            int oc = g*16 + gate*4 + s;
            wv = W[((oc*5 + ic)*3 + kr)*3 + kc];
        }
        wdst[i] = (short)__builtin_bit_cast(unsigned short, __float2bfloat16(wv));
    } else if (i < WFRAG_SHORTS + BIAS_FLOATS) {
        int idx = i - WFRAG_SHORTS;
        int g = idx >> 4;
        int r = idx & 15;
        int s = r >> 2, gate = r & 3;
        bdst[idx] = b[g*16 + gate*4 + s];   // [g][s][gate]
    }
}

__launch_bounds__(256, 4)
__global__ void convlstm_mfma(const float* __restrict__ x,
                              const float* __restrict__ h,
                              const float* __restrict__ c,
                              const short* __restrict__ wfrag,
                              const float* __restrict__ biasp,
                              float* __restrict__ out) {
    __shared__ unsigned int lds[LDS_U32];   // bf16 pairs

    const int t    = threadIdx.x;
    const int bid  = blockIdx.x;
    const int bg   = bid >> 7;          // (b*19+g)
    const int tile = bid & 127;
    const int tr0  = (tile >> 3) * TH;
    const int tc0  = (tile & 7)  * TW;
    const int g    = bg % NG;

    const int w  = t >> 6;     // wave 0..3 (owns tile rows w*4..w*4+3)
    const int l  = t & 63;
    const int q  = l >> 4;     // slab
    const int li = l & 15;     // B column -> pixel tile-col 4*li + n

    // ---- prefetch c as 4 nontemporal 16B loads (read-once: skip caches) ----
    const int NC_OFF   = BATCH * NG * 4 * HW;   // 39,845,888
    const int rowbase0 = (bg*4 + q)*HW + (tr0 + w*4)*WIDTH + tc0 + 4*li;
    f32x4 cp[4];
    #pragma unroll
    for (int tr4 = 0; tr4 < 4; ++tr4)
        cp[tr4] = __builtin_nontemporal_load(
            reinterpret_cast<const f32x4*>(c + rowbase0 + tr4*WIDTH));

    // ---- A fragments + bias ----
    const short8* ap = reinterpret_cast<const short8*>(wfrag + (g*64 + l)*16);
    const short8 a_lo = ap[0];
    const short8 a_hi = ap[1];
    f32x4 bias4;
    {
        float4 bv = *reinterpret_cast<const float4*>(biasp + g*16 + q*4);
        bias4[0] = bv.x; bias4[1] = bv.y; bias4[2] = bv.z; bias4[3] = bv.w;
    }

    // ---- stage 5-channel halo as packed bf16 pairs (convert once) ----
    const float* xb = x + bg * HW;
    const float* hb = h + (bg * 4) * HW;
    for (int p = t; p < LDS_U32; p += 256) {
        int ch  = p / CH_U32;  int rem = p - ch * CH_U32;
        int r   = rem / HALO_CU;
        int j   = rem - r * HALO_CU;
        int gr  = tr0 + r - 1;
        int gc  = tc0 + 2*j - 1;
        const float* base = (ch == 0) ? xb : hb + (ch - 1) * HW;
        float v0 = 0.0f, v1 = 0.0f;
        if (gr >= 0 && gr < HEIGHT) {
            const float* rowp = base + gr * WIDTH;
            if (gc >= 0 && gc < WIDTH) v0 = rowp[gc];
            if (gc + 1 < WIDTH)        v1 = rowp[gc + 1];   // gc+1 >= 0 always
        }
        lds[p] = bfbits(v0) | (bfbits(v1) << 16);
    }
    __syncthreads();

    // ---- per-lane combo base byte offsets (8B-aligned by construction) ----
    int cbase[4];
    #pragma unroll
    for (int i = 0; i < 4; ++i) {
        int m = (i < 2) ? (2*q + i) : (8 + 2*q + (i - 2));
        if (m > 14) m = 14;                         // m==15 pad: weight is 0
        cbase[i] = (m/3)*(CH_U32*4) + (m%3)*(HALO_CU*4) + 8*li;
    }
    const char* ldsb = reinterpret_cast<const char*>(lds);

    #pragma unroll
    for (int tr4 = 0; tr4 < 4; ++tr4) {
        const int tr = w*4 + tr4;
        // one 16B window read per combo serves all 4 chunks
        uint2 dv[4][2];
        #pragma unroll
        for (int i = 0; i < 4; ++i) {
            const uint2* pp = reinterpret_cast<const uint2*>(
                ldsb + cbase[i] + tr * (HALO_CU*4));
            dv[i][0] = pp[0];       // ds_read_b64: cols 4li..4li+3
            dv[i][1] = pp[1];       // ds_read_b64: cols 4li+4..4li+7
        }
        float nh4[4], nc4[4];
        #pragma unroll
        for (int n = 0; n < 4; ++n) {
            u32x4 blo_u, bhi_u;
            #pragma unroll
            for (int i = 0; i < 4; ++i) {
                const unsigned int d0 = dv[i][0].x, d1 = dv[i][0].y;
                const unsigned int d2 = dv[i][1].x, d3 = dv[i][1].y;
                unsigned int w0, w1;
                if (n == 0)      { w0 = d0;           w1 = d1;           }
                else if (n == 1) { w0 = fsh16(d1,d0); w1 = fsh16(d2,d1); }
                else if (n == 2) { w0 = d1;           w1 = d2;           }
                else             { w0 = fsh16(d2,d1); w1 = fsh16(d3,d2); }
                if (i < 2) { blo_u[2*i]     = w0; blo_u[2*i+1]     = w1; }
                else       { bhi_u[2*(i-2)] = w0; bhi_u[2*(i-2)+1] = w1; }
            }
            const short8 blo = __builtin_bit_cast(short8, blo_u);
            const short8 bhi = __builtin_bit_cast(short8, bhi_u);

            f32x4 acc = bias4;
            acc = __builtin_amdgcn_mfma_f32_16x16x32_bf16(a_lo, blo, acc, 0, 0, 0);
            acc = __builtin_amdgcn_mfma_f32_16x16x32_bf16(a_hi, bhi, acc, 0, 0, 0);

            // lane-local LSTM epilogue: acc = {i,f,o,g} for (pixel, slab=q)
            const float cv = cp[tr4][n];
            const float iv = fsigmoid(acc[0]);
            const float fv = fsigmoid(acc[1]);
            const float ov = fsigmoid(acc[2]);
            const float gv = ftanh   (acc[3]);
            const float nc = fv * cv + iv * gv;
            nc4[n] = nc;
            nh4[n] = ov * ftanh(nc);
        }
        // dense 16B nontemporal stores (write-once: stream past L2)
        const int rowchan = rowbase0 + tr4*WIDTH;
        f32x4 nhv; nhv[0]=nh4[0]; nhv[1]=nh4[1]; nhv[2]=nh4[2]; nhv[3]=nh4[3];
        f32x4 ncv; ncv[0]=nc4[0]; ncv[1]=nc4[1]; ncv[2]=nc4[2]; ncv[3]=nc4[3];
        __builtin_nontemporal_store(nhv, reinterpret_cast<f32x4*>(out + rowchan));
        __builtin_nontemporal_store(ncv, reinterpret_cast<f32x4*>(out + NC_OFF + rowchan));
    }
}

extern "C" void kernel_launch(void* const* d_in, const int* in_sizes, int n_in,
                              void* d_out, int out_size, void* d_ws, size_t ws_size,
                              hipStream_t stream) {
    (void)in_sizes; (void)n_in; (void)out_size; (void)ws_size;
    const float* x = (const float*)d_in[0];
    const float* h = (const float*)d_in[1];
    const float* c = (const float*)d_in[2];
    const float* W = (const float*)d_in[3];
    const float* b = (const float*)d_in[4];
    float* out = (float*)d_out;

    short* wdst = (short*)d_ws;                                         // 38,912 B
    float* bdst = (float*)((char*)d_ws + WFRAG_SHORTS * sizeof(short)); // +1,216 B

    hipLaunchKernelGGL(wxform_kernel,
                       dim3((WFRAG_SHORTS + BIAS_FLOATS + 255) / 256), dim3(256),
                       0, stream, W, b, wdst, bdst);
    hipLaunchKernelGGL(convlstm_mfma, dim3(BATCH * NG * 128), dim3(256),
                       0, stream, x, h, c, (const short*)wdst, bdst, out);
}

// Round 7
// 143.988 us; speedup vs baseline: 2.4417x; 1.0174x over previous
//
#include <hip/hip_runtime.h>
#include <hip/hip_bf16.h>

// ---------------- problem constants ----------------
#define NG      19
#define HEIGHT  256
#define WIDTH   512
#define HW      (HEIGHT*WIDTH)        // 131072
#define BATCH   4
#define TH      16                    // tile rows
#define NT      4                     // tiles per block (same row band, consecutive cols)
#define HALO_R  18
#define HALO_CU 34                    // u32 cols = 68 bf16 cols, origin tc0-2
#define CH_U32  (HALO_R*HALO_CU)      // 612
#define LDS_U32 (5*CH_U32)            // 3060 u32 = 12240 B
#define STAGE_TOT LDS_U32             // 3060 float2 loads per tile
#define STAGE_PER 12                  // ceil(3060/256)
#define WFRAG_SHORTS (NG*64*16)
#define BIAS_FLOATS (NG*16)

typedef __attribute__((ext_vector_type(8))) short short8;
typedef __attribute__((ext_vector_type(4))) float f32x4;
typedef __attribute__((ext_vector_type(2))) float f32x2;
typedef __attribute__((ext_vector_type(4))) unsigned int u32x4;

static __device__ __forceinline__ unsigned int bfbits(float f) {
    return (unsigned int)__builtin_bit_cast(unsigned short, __float2bfloat16(f));
}
static __device__ __forceinline__ unsigned int pack2(float lo, float hi) {
    return bfbits(lo) | (bfbits(hi) << 16);
}
static __device__ __forceinline__ unsigned int fsh16(unsigned int hi, unsigned int lo) {
    return (unsigned int)((((unsigned long long)hi << 32) | lo) >> 16);  // v_alignbit
}
// rcp(1 + 2^a) : sigma(A) when a = -1.4427*A (scale folded into weights)
static __device__ __forceinline__ float sig2(float a) {
    return __builtin_amdgcn_rcpf(1.0f + __builtin_amdgcn_exp2f(a));
}
static __device__ __forceinline__ float ftanh(float x) {
    return 2.0f * __builtin_amdgcn_rcpf(1.0f + __builtin_amdgcn_exp2f(-2.88539008f * x)) - 1.0f;
}

// K enumeration: k = m*4 + kc, m = (ic*3+kr) in 0..14, kc in 0..3.
// kc==3 and m==15 are zero-weight pad slots.
// A row = oc_perm = s*4 + gate -> D gives lane-local gates per (pixel,slab).
// exp2 scales folded: gates i,f,o scaled by -1.4427, gate g by -2.8854.
__global__ void wxform_kernel(const float* __restrict__ W,
                              const float* __restrict__ b,
                              short* __restrict__ wdst,
                              float* __restrict__ bdst) {
    int i = blockIdx.x * 256 + threadIdx.x;
    if (i < WFRAG_SHORTS) {
        int g   = i / 1024;
        int r   = i & 1023;
        int l   = r >> 4;          // lane 0..63
        int j   = r & 15;          // element 0..15
        int q   = l >> 4;
        int row = l & 15;          // oc_perm = s*4 + gate
        int s    = row >> 2;
        int gate = row & 3;
        int half = j >> 3;
        int jj   = j & 7;
        int m  = 8*half + 2*q + (jj >> 2);   // (ic,kr) combo index
        int kc = jj & 3;
        float wv = 0.0f;
        if (m <= 14 && kc < 3) {
            int ic = m / 3, kr = m % 3;
            int oc = g*16 + gate*4 + s;
            float scale = (gate == 3) ? -2.88539008f : -1.44269504f;
            wv = scale * W[((oc*5 + ic)*3 + kr)*3 + kc];
        }
        wdst[i] = (short)__builtin_bit_cast(unsigned short, __float2bfloat16(wv));
    } else if (i < WFRAG_SHORTS + BIAS_FLOATS) {
        int idx = i - WFRAG_SHORTS;
        int g = idx >> 4;
        int r = idx & 15;
        int s = r >> 2, gate = r & 3;
        float scale = (gate == 3) ? -2.88539008f : -1.44269504f;
        bdst[idx] = scale * b[g*16 + gate*4 + s];   // [g][s][gate]
    }
}

__launch_bounds__(256, 4)
__global__ void convlstm_mfma(const float* __restrict__ x,
                              const float* __restrict__ h,
                              const float* __restrict__ c,
                              const short* __restrict__ wfrag,
                              const float* __restrict__ biasp,
                              float* __restrict__ out) {
    __shared__ unsigned int lds[LDS_U32];   // bf16 pairs, cols gc = tc0-2+2j .. +1

    const int t     = threadIdx.x;
    const int bid   = blockIdx.x;
    const int plane = bid >> 5;            // (b*19+g)
    const int rem   = bid & 31;
    const int tr0   = (rem >> 1) * TH;     // row band
    const int tcb   = (rem & 1) * 256;     // first tile col; tiles at tcb+64*tt
    const int g     = plane % NG;

    const int w  = t >> 6;     // wave: owns tile rows w*4..w*4+3
    const int l  = t & 63;
    const int q  = l >> 4;     // slab
    const int li = l & 15;     // B column -> pixel tile-col 4*li + n

    // ---- A fragments + bias (scales folded) ----
    const short8* ap = reinterpret_cast<const short8*>(wfrag + (g*64 + l)*16);
    const short8 a_lo = ap[0];
    const short8 a_hi = ap[1];
    f32x4 bias4;
    {
        float4 bv = *reinterpret_cast<const float4*>(biasp + g*16 + q*4);
        bias4[0] = bv.x; bias4[1] = bv.y; bias4[2] = bv.z; bias4[3] = bv.w;
    }

    // ---- staging metadata (tile-invariant; tile adds +tc0 to the offset) ----
    const float* xb = x + plane * HW;
    const float* hb = h + (plane * 4) * HW;
    int soff[STAGE_PER];     // float offset from (isX ? xb : hb) at tc0 = 0
    int meta[STAGE_PER];     // [15:0] lds idx | bit16 valid | bit17 rowok | bit18 j2==0 | bit19 j2==33 | bit20 isX
    #pragma unroll
    for (int k = 0; k < STAGE_PER; ++k) {
        int p  = t + 256*k;
        int v  = (p < STAGE_TOT) ? 1 : 0;
        int pp = v ? p : 0;
        int ch = pp / CH_U32;
        int r2 = pp - ch*CH_U32;
        int r  = r2 / HALO_CU;
        int j2 = r2 - r*HALO_CU;
        int gr = tr0 + r - 1;
        int rok = ((unsigned)gr < HEIGHT) ? 1 : 0;
        int isx = (ch == 0) ? 1 : 0;
        soff[k] = (isx ? 0 : (ch-1)*HW) + gr*WIDTH + 2*j2 - 2;
        meta[k] = (ch*CH_U32 + r*HALO_CU + j2)
                | (v << 16) | (rok << 17)
                | ((j2 == 0) ? (1<<18) : 0) | ((j2 == 33) ? (1<<19) : 0)
                | (isx << 20);
    }

    // ---- per-lane combo base byte offsets (8B-aligned: all terms mult of 8) ----
    int cbase[4];
    #pragma unroll
    for (int i = 0; i < 4; ++i) {
        int m = (i < 2) ? (2*q + i) : (8 + 2*q + (i - 2));
        if (m > 14) m = 14;                        // m==15 pad: weight is 0
        cbase[i] = (m/3)*(CH_U32*4) + (m%3)*(HALO_CU*4) + 8*li;
    }
    const char* ldsb = reinterpret_cast<const char*>(lds);
    const int NC_OFF = BATCH * NG * 4 * HW;   // 39,845,888

    f32x2 pf[STAGE_PER];

    auto stage_issue = [&](int tc0) {
        const bool lt = (tc0 == 0), rt = (tc0 == 448);
        #pragma unroll
        for (int k = 0; k < STAGE_PER; ++k) {
            const int mk = meta[k];
            bool ok = (mk & (1<<16)) && (mk & (1<<17))
                   && !(lt && (mk & (1<<18))) && !(rt && (mk & (1<<19)));
            const float* bp = (mk & (1<<20)) ? xb : hb;
            f32x2 z; z[0] = 0.0f; z[1] = 0.0f;
            pf[k] = ok ? *reinterpret_cast<const f32x2*>(bp + soff[k] + tc0) : z;
        }
    };
    auto stage_write = [&]() {      // compiler inserts vmcnt waits for pf deps
        #pragma unroll
        for (int k = 0; k < STAGE_PER; ++k) {
            const int mk = meta[k];
            if (mk & (1<<16))
                lds[mk & 0xFFFF] = pack2(pf[k][0], pf[k][1]);
        }
    };

    // prologue: stage tile0, put tile1's loads in flight
    stage_issue(tcb);
    stage_write();
    stage_issue(tcb + 64);
    asm volatile("s_waitcnt lgkmcnt(0)" ::: "memory");
    __builtin_amdgcn_s_barrier();           // buf ready (no vmcnt drain!)
    asm volatile("" ::: "memory");

    #pragma unroll 1
    for (int tt = 0; tt < NT; ++tt) {
        const int tc0 = tcb + 64*tt;
        const int rowbase0 = (plane*4 + q)*HW + (tr0 + w*4)*WIDTH + tc0 + 4*li;

        // c prefetch, nontemporal (read-once)
        f32x4 cp[4];
        #pragma unroll
        for (int tr4 = 0; tr4 < 4; ++tr4)
            cp[tr4] = __builtin_nontemporal_load(
                reinterpret_cast<const f32x4*>(c + rowbase0 + tr4*WIDTH));

        #pragma unroll
        for (int tr4 = 0; tr4 < 4; ++tr4) {
            const int tr = w*4 + tr4;
            uint2 dv[4][2];
            #pragma unroll
            for (int i = 0; i < 4; ++i) {
                const uint2* pp2 = reinterpret_cast<const uint2*>(
                    ldsb + cbase[i] + tr*(HALO_CU*4));
                dv[i][0] = pp2[0];        // ds_read_b64
                dv[i][1] = pp2[1];
            }
            float nh4[4], nc4[4];
            #pragma unroll
            for (int n = 0; n < 4; ++n) {
                // origin -2 window table: j0 = 4li+n+1, d = cols 4li..4li+7
                u32x4 blo_u, bhi_u;
                #pragma unroll
                for (int i = 0; i < 4; ++i) {
                    const unsigned d0 = dv[i][0].x, d1 = dv[i][0].y;
                    const unsigned d2 = dv[i][1].x, d3 = dv[i][1].y;
                    unsigned w0, w1;
                    if (n == 0)      { w0 = fsh16(d1,d0); w1 = fsh16(d2,d1); }
                    else if (n == 1) { w0 = d1;           w1 = d2;           }
                    else if (n == 2) { w0 = fsh16(d2,d1); w1 = fsh16(d3,d2); }
                    else             { w0 = d2;           w1 = d3;           }
                    if (i < 2) { blo_u[2*i]     = w0; blo_u[2*i+1]     = w1; }
                    else       { bhi_u[2*(i-2)] = w0; bhi_u[2*(i-2)+1] = w1; }
                }
                const short8 blo = __builtin_bit_cast(short8, blo_u);
                const short8 bhi = __builtin_bit_cast(short8, bhi_u);

                f32x4 acc = bias4;
                acc = __builtin_amdgcn_mfma_f32_16x16x32_bf16(a_lo, blo, acc, 0, 0, 0);
                acc = __builtin_amdgcn_mfma_f32_16x16x32_bf16(a_hi, bhi, acc, 0, 0, 0);

                // lane-local LSTM epilogue (exp2 scales pre-folded into acc)
                const float cv = cp[tr4][n];
                const float iv = sig2(acc[0]);
                const float fv = sig2(acc[1]);
                const float ov = sig2(acc[2]);
                const float gv = 2.0f * sig2(acc[3]) - 1.0f;
                const float nc = fv * cv + iv * gv;
                nc4[n] = nc;
                nh4[n] = ov * ftanh(nc);
            }
            const int rowchan = rowbase0 + tr4*WIDTH;
            f32x4 nhv; nhv[0]=nh4[0]; nhv[1]=nh4[1]; nhv[2]=nh4[2]; nhv[3]=nh4[3];
            f32x4 ncv; ncv[0]=nc4[0]; ncv[1]=nc4[1]; ncv[2]=nc4[2]; ncv[3]=nc4[3];
            __builtin_nontemporal_store(nhv, reinterpret_cast<f32x4*>(out + rowchan));
            __builtin_nontemporal_store(ncv, reinterpret_cast<f32x4*>(out + NC_OFF + rowchan));
        }

        if (tt + 1 < NT) {
            // all waves done reading this tile's LDS (reads consumed pre-barrier)
            asm volatile("" ::: "memory");
            __builtin_amdgcn_s_barrier();
            asm volatile("" ::: "memory");
            stage_write();                          // tile tt+1 (loads issued last iter)
            if (tt + 2 < NT) stage_issue(tcb + 64*(tt + 2));   // in flight under next compute
            asm volatile("s_waitcnt lgkmcnt(0)" ::: "memory");
            __builtin_amdgcn_s_barrier();
            asm volatile("" ::: "memory");
        }
    }
}

extern "C" void kernel_launch(void* const* d_in, const int* in_sizes, int n_in,
                              void* d_out, int out_size, void* d_ws, size_t ws_size,
                              hipStream_t stream) {
    (void)in_sizes; (void)n_in; (void)out_size; (void)ws_size;
    const float* x = (const float*)d_in[0];
    const float* h = (const float*)d_in[1];
    const float* c = (const float*)d_in[2];
    const float* W = (const float*)d_in[3];
    const float* b = (const float*)d_in[4];
    float* out = (float*)d_out;

    short* wdst = (short*)d_ws;                                         // 38,912 B
    float* bdst = (float*)((char*)d_ws + WFRAG_SHORTS * sizeof(short)); // +1,216 B

    hipLaunchKernelGGL(wxform_kernel,
                       dim3((WFRAG_SHORTS + BIAS_FLOATS + 255) / 256), dim3(256),
                       0, stream, W, b, wdst, bdst);
    hipLaunchKernelGGL(convlstm_mfma, dim3(BATCH * NG * 32), dim3(256),
                       0, stream, x, h, c, (const short*)wdst, bdst, out);
}

// Round 8
// 143.382 us; speedup vs baseline: 2.4520x; 1.0042x over previous
//
#include <hip/hip_runtime.h>
#include <hip/hip_bf16.h>

// ---------------- problem constants ----------------
#define NG      19
#define HEIGHT  256
#define WIDTH   512
#define HW      (HEIGHT*WIDTH)        // 131072
#define BATCH   4
#define TH      16                    // tile rows
#define NT      4                     // tiles per block (same row band, consecutive cols)
#define HALO_R  18
#define HALO_CU 34                    // u32 cols = 68 bf16 cols, origin tc0-2
#define CH_U32  (HALO_R*HALO_CU)      // 612
#define LDS_U32 (5*CH_U32)            // 3060 u32 = 12240 B per buffer
#define STAGE_TOT LDS_U32
#define STAGE_PER 12                  // ceil(3060/256)
#define WFRAG_SHORTS (NG*64*16)
#define BIAS_FLOATS (NG*16)

typedef __attribute__((ext_vector_type(8))) short short8;
typedef __attribute__((ext_vector_type(4))) float f32x4;
typedef __attribute__((ext_vector_type(2))) float f32x2;
typedef __attribute__((ext_vector_type(4))) unsigned int u32x4;

static __device__ __forceinline__ unsigned int bfbits(float f) {
    return (unsigned int)__builtin_bit_cast(unsigned short, __float2bfloat16(f));
}
static __device__ __forceinline__ unsigned int pack2(float lo, float hi) {
    return bfbits(lo) | (bfbits(hi) << 16);
}
static __device__ __forceinline__ unsigned int fsh16(unsigned int hi, unsigned int lo) {
    return (unsigned int)((((unsigned long long)hi << 32) | lo) >> 16);  // v_alignbit
}

// K enumeration: k = m*4 + kc, m = (ic*3+kr) in 0..14, kc in 0..3.
// kc==3 and m==15 are zero-weight pad slots.
// A row = oc_perm = s*4 + gate -> D gives lane-local gates per (pixel,slab).
// exp2 scales folded: gates i,f,o scaled by -1.4427 (a = -1.4427*A so that
// sigma(A) = 1/(1+2^a)), gate g scaled by -2.8854 (tanh(A) = (1-2^a)/(1+2^a)).
__global__ void wxform_kernel(const float* __restrict__ W,
                              const float* __restrict__ b,
                              short* __restrict__ wdst,
                              float* __restrict__ bdst) {
    int i = blockIdx.x * 256 + threadIdx.x;
    if (i < WFRAG_SHORTS) {
        int g   = i / 1024;
        int r   = i & 1023;
        int l   = r >> 4;          // lane 0..63
        int j   = r & 15;          // element 0..15
        int q   = l >> 4;
        int row = l & 15;          // oc_perm = s*4 + gate
        int s    = row >> 2;
        int gate = row & 3;
        int half = j >> 3;
        int jj   = j & 7;
        int m  = 8*half + 2*q + (jj >> 2);   // (ic,kr) combo index
        int kc = jj & 3;
        float wv = 0.0f;
        if (m <= 14 && kc < 3) {
            int ic = m / 3, kr = m % 3;
            int oc = g*16 + gate*4 + s;
            float scale = (gate == 3) ? -2.88539008f : -1.44269504f;
            wv = scale * W[((oc*5 + ic)*3 + kr)*3 + kc];
        }
        wdst[i] = (short)__builtin_bit_cast(unsigned short, __float2bfloat16(wv));
    } else if (i < WFRAG_SHORTS + BIAS_FLOATS) {
        int idx = i - WFRAG_SHORTS;
        int g = idx >> 4;
        int r = idx & 15;
        int s = r >> 2, gate = r & 3;
        float scale = (gate == 3) ? -2.88539008f : -1.44269504f;
        bdst[idx] = scale * b[g*16 + gate*4 + s];   // [g][s][gate]
    }
}

__launch_bounds__(256, 3)
__global__ void convlstm_mfma(const float* __restrict__ x,
                              const float* __restrict__ h,
                              const float* __restrict__ c,
                              const short* __restrict__ wfrag,
                              const float* __restrict__ biasp,
                              float* __restrict__ out) {
    __shared__ unsigned int lds[2][LDS_U32];   // double-buffered bf16-pair halo

    const int t     = threadIdx.x;
    const int bid   = blockIdx.x;
    const int plane = bid >> 5;            // (b*19+g)
    const int rem   = bid & 31;
    const int tr0   = (rem >> 1) * TH;     // row band
    const int tcb   = (rem & 1) * 256;     // tiles at tcb + 64*tt
    const int g     = plane % NG;

    const int w  = t >> 6;     // wave: owns tile rows w*4..w*4+3
    const int l  = t & 63;
    const int q  = l >> 4;     // slab
    const int li = l & 15;     // B column -> pixel tile-col 4*li + n

    // ---- A fragments + bias (scales folded) ----
    const short8* ap = reinterpret_cast<const short8*>(wfrag + (g*64 + l)*16);
    const short8 a_lo = ap[0];
    const short8 a_hi = ap[1];
    f32x4 bias4;
    {
        float4 bv = *reinterpret_cast<const float4*>(biasp + g*16 + q*4);
        bias4[0] = bv.x; bias4[1] = bv.y; bias4[2] = bv.z; bias4[3] = bv.w;
    }

    // ---- staging metadata (tile-invariant; tile adds +tc0) ----
    const float* xb = x + plane * HW;
    const float* hb = h + (plane * 4) * HW;
    int soff[STAGE_PER];
    int meta[STAGE_PER];   // [15:0] lds idx | b16 valid | b17 rowok | b18 j2==0 | b19 j2==33 | b20 isX
    #pragma unroll
    for (int k = 0; k < STAGE_PER; ++k) {
        int p  = t + 256*k;
        int v  = (p < STAGE_TOT) ? 1 : 0;
        int pp = v ? p : 0;
        int ch = pp / CH_U32;
        int r2 = pp - ch*CH_U32;
        int r  = r2 / HALO_CU;
        int j2 = r2 - r*HALO_CU;
        int gr = tr0 + r - 1;
        int rok = ((unsigned)gr < HEIGHT) ? 1 : 0;
        int isx = (ch == 0) ? 1 : 0;
        soff[k] = (isx ? 0 : (ch-1)*HW) + gr*WIDTH + 2*j2 - 2;
        meta[k] = (ch*CH_U32 + r*HALO_CU + j2)
                | (v << 16) | (rok << 17)
                | ((j2 == 0) ? (1<<18) : 0) | ((j2 == 33) ? (1<<19) : 0)
                | (isx << 20);
    }

    // ---- per-lane combo base byte offsets (8B-aligned) ----
    int cbase[4];
    #pragma unroll
    for (int i = 0; i < 4; ++i) {
        int m = (i < 2) ? (2*q + i) : (8 + 2*q + (i - 2));
        if (m > 14) m = 14;                        // m==15 pad: weight is 0
        cbase[i] = (m/3)*(CH_U32*4) + (m%3)*(HALO_CU*4) + 8*li;
    }
    const int NC_OFF = BATCH * NG * 4 * HW;   // 39,845,888

    f32x2 pf[STAGE_PER];

    auto stage_issue = [&](int tc0) {
        const bool lt = (tc0 == 0), rt = (tc0 == 448);
        #pragma unroll
        for (int k = 0; k < STAGE_PER; ++k) {
            const int mk = meta[k];
            bool ok = (mk & (1<<16)) && (mk & (1<<17))
                   && !(lt && (mk & (1<<18))) && !(rt && (mk & (1<<19)));
            const float* bp = (mk & (1<<20)) ? xb : hb;
            f32x2 z; z[0] = 0.0f; z[1] = 0.0f;
            pf[k] = ok ? *reinterpret_cast<const f32x2*>(bp + soff[k] + tc0) : z;
        }
    };
    auto stage_write = [&](unsigned int* buf) {
        #pragma unroll
        for (int k = 0; k < STAGE_PER; ++k) {
            const int mk = meta[k];
            if (mk & (1<<16))
                buf[mk & 0xFFFF] = pack2(pf[k][0], pf[k][1]);
        }
    };
    auto cload = [&](int tc0, f32x4 (&cp)[4]) {
        const int rowbase0 = (plane*4 + q)*HW + (tr0 + w*4)*WIDTH + tc0 + 4*li;
        #pragma unroll
        for (int tr4 = 0; tr4 < 4; ++tr4)
            cp[tr4] = __builtin_nontemporal_load(
                reinterpret_cast<const f32x4*>(c + rowbase0 + tr4*WIDTH));
    };

    auto do_tile = [&](int tc0, const unsigned int* buf, const f32x4 (&cp)[4]) {
        const char* ldsb = reinterpret_cast<const char*>(buf);
        const int rowbase0 = (plane*4 + q)*HW + (tr0 + w*4)*WIDTH + tc0 + 4*li;
        #pragma unroll
        for (int tr4 = 0; tr4 < 4; ++tr4) {
            const int tr = w*4 + tr4;
            uint2 dv[4][2];
            #pragma unroll
            for (int i = 0; i < 4; ++i) {
                const uint2* pp2 = reinterpret_cast<const uint2*>(
                    ldsb + cbase[i] + tr*(HALO_CU*4));
                dv[i][0] = pp2[0];        // ds_read_b64: cols 4li..4li+3
                dv[i][1] = pp2[1];        // ds_read_b64: cols 4li+4..4li+7
            }
            float nh4[4], nc4[4];
            #pragma unroll
            for (int n = 0; n < 4; ++n) {
                // window cols (lds, origin tc0-2): 4li+n+1 .. 4li+n+4
                u32x4 blo_u, bhi_u;
                #pragma unroll
                for (int i = 0; i < 4; ++i) {
                    const unsigned d0 = dv[i][0].x, d1 = dv[i][0].y;
                    const unsigned d2 = dv[i][1].x, d3 = dv[i][1].y;
                    unsigned w0, w1;
                    if (n == 0)      { w0 = fsh16(d1,d0); w1 = fsh16(d2,d1); }
                    else if (n == 1) { w0 = d1;           w1 = d2;           }
                    else if (n == 2) { w0 = fsh16(d2,d1); w1 = fsh16(d3,d2); }
                    else             { w0 = d2;           w1 = d3;           }
                    if (i < 2) { blo_u[2*i]     = w0; blo_u[2*i+1]     = w1; }
                    else       { bhi_u[2*(i-2)] = w0; bhi_u[2*(i-2)+1] = w1; }
                }
                const short8 blo = __builtin_bit_cast(short8, blo_u);
                const short8 bhi = __builtin_bit_cast(short8, bhi_u);

                f32x4 acc = bias4;
                acc = __builtin_amdgcn_mfma_f32_16x16x32_bf16(a_lo, blo, acc, 0, 0, 0);
                acc = __builtin_amdgcn_mfma_f32_16x16x32_bf16(a_hi, bhi, acc, 0, 0, 0);

                // fused-reciprocal LSTM epilogue: 5 exp2 + 2 rcp per pixel.
                // u=2^ai, v=2^af, wo=2^ao, z=2^ag (scales pre-folded in MFMA).
                // nc = c/(1+v) + (1-z)/((1+u)(1+z))
                //    = [c*(1+u)(1+z) + (1-z)(1+v)] * rcp((1+v)(1+u)(1+z))
                // nh = (1-t)*rcp((1+wo)(1+t)),  t = 2^(-2.8854*nc)
                const float cv = cp[tr4][n];
                const float u  = __builtin_amdgcn_exp2f(acc[0]);
                const float v  = __builtin_amdgcn_exp2f(acc[1]);
                const float wo = __builtin_amdgcn_exp2f(acc[2]);
                const float z  = __builtin_amdgcn_exp2f(acc[3]);
                const float pu = 1.0f + u, pv = 1.0f + v;
                const float pw = 1.0f + wo, pz = 1.0f + z;
                const float puz = pu * pz;
                const float r1  = __builtin_amdgcn_rcpf(pv * puz);
                const float nc  = fmaf(cv, puz, (1.0f - z) * pv) * r1;
                const float tt2 = __builtin_amdgcn_exp2f(-2.88539008f * nc);
                const float r2  = __builtin_amdgcn_rcpf(pw * (1.0f + tt2));
                nc4[n] = nc;
                nh4[n] = (1.0f - tt2) * r2;
            }
            const int rowchan = rowbase0 + tr4*WIDTH;
            f32x4 nhv; nhv[0]=nh4[0]; nhv[1]=nh4[1]; nhv[2]=nh4[2]; nhv[3]=nh4[3];
            f32x4 ncv; ncv[0]=nc4[0]; ncv[1]=nc4[1]; ncv[2]=nc4[2]; ncv[3]=nc4[3];
            __builtin_nontemporal_store(nhv, reinterpret_cast<f32x4*>(out + rowchan));
            __builtin_nontemporal_store(ncv, reinterpret_cast<f32x4*>(out + NC_OFF + rowchan));
        }
    };

    f32x4 cpA[4], cpB[4];

    // ---- prologue: buf0 = t0; t1 loads + c(t0), c(t1) in flight ----
    stage_issue(tcb);
    stage_write(lds[0]);
    stage_issue(tcb + 64);
    cload(tcb,      cpA);
    cload(tcb + 64, cpB);
    asm volatile("s_waitcnt lgkmcnt(0)" ::: "memory");
    __builtin_amdgcn_s_barrier();
    asm volatile("" ::: "memory");

    // ---- tile 0: compute(t0,buf0) || write t1->buf1, issue t2, c(t2) ----
    do_tile(tcb, lds[0], cpA);
    stage_write(lds[1]);
    stage_issue(tcb + 128);
    cload(tcb + 128, cpA);
    asm volatile("s_waitcnt lgkmcnt(0)" ::: "memory");
    __builtin_amdgcn_s_barrier();
    asm volatile("" ::: "memory");

    // ---- tile 1 ----
    do_tile(tcb + 64, lds[1], cpB);
    stage_write(lds[0]);
    stage_issue(tcb + 192);
    cload(tcb + 192, cpB);
    asm volatile("s_waitcnt lgkmcnt(0)" ::: "memory");
    __builtin_amdgcn_s_barrier();
    asm volatile("" ::: "memory");

    // ---- tile 2 ----
    do_tile(tcb + 128, lds[0], cpA);
    stage_write(lds[1]);
    asm volatile("s_waitcnt lgkmcnt(0)" ::: "memory");
    __builtin_amdgcn_s_barrier();
    asm volatile("" ::: "memory");

    // ---- tile 3 ----
    do_tile(tcb + 192, lds[1], cpB);
}

extern "C" void kernel_launch(void* const* d_in, const int* in_sizes, int n_in,
                              void* d_out, int out_size, void* d_ws, size_t ws_size,
                              hipStream_t stream) {
    (void)in_sizes; (void)n_in; (void)out_size; (void)ws_size;
    const float* x = (const float*)d_in[0];
    const float* h = (const float*)d_in[1];
    const float* c = (const float*)d_in[2];
    const float* W = (const float*)d_in[3];
    const float* b = (const float*)d_in[4];
    float* out = (float*)d_out;

    short* wdst = (short*)d_ws;                                         // 38,912 B
    float* bdst = (float*)((char*)d_ws + WFRAG_SHORTS * sizeof(short)); // +1,216 B

    hipLaunchKernelGGL(wxform_kernel,
                       dim3((WFRAG_SHORTS + BIAS_FLOATS + 255) / 256), dim3(256),
                       0, stream, W, b, wdst, bdst);
    hipLaunchKernelGGL(convlstm_mfma, dim3(BATCH * NG * 32), dim3(256),
                       0, stream, x, h, c, (const short*)wdst, bdst, out);
}